// Round 2
// baseline (756.348 us; speedup 1.0000x reference)
//
#include <hip/hip_runtime.h>
#include <stdint.h>

// out = relu(W1b·relu(Wf1·z1 + bf1) + b1b) + relu(W2b·relu(Wf2·z2 + bf2) + b2b)
// z1 = bone, z2 = t_bone; BN folded into Wf/bf (fused per (path, v)).
// k3 v2: block = (n, 32-t chunk), 5 waves = 5 v's sharing cooperatively
// LDS-staged x rows (float4 coalesced); layer1+layer2 via mfma_f32_16x16x32_bf16.

#define T_ 300

typedef __attribute__((ext_vector_type(8))) short bf16x8;
typedef __attribute__((ext_vector_type(4))) float f32x4;

__device__ __constant__ int PARENT_D[25] = {1,20,20,2,20,4,5,6,20,8,9,10,0,12,13,14,0,16,17,18,20,22,7,24,11};

static __device__ __forceinline__ unsigned short f2bf(float f) {
  unsigned int u = __float_as_uint(f);
  unsigned int r = (u + 0x7FFFu + ((u >> 16) & 1u)) >> 16;  // RNE, no NaN inputs expected
  return (unsigned short)r;
}

__global__ void k0_zero(float* p, int cnt) {
  int i = blockIdx.x * blockDim.x + threadIdx.x;
  if (i < cnt) p[i] = 0.f;
}

// ---- stats: sum/sumsq of bone and t_bone per BN channel (ch = c*25+v) ----
// grid (n=256, s=4): block handles rows [s*75, s*75+75) (+1 boundary row for t_bone).
// bone value carried across iterations -> 2 LDS reads/row instead of 4.
// Atomics go to per-s slabs (stride 304 floats) to cut per-line contention 4x.
__global__ void k1_stats(const float* __restrict__ x, float* __restrict__ stats) {
  __shared__ float rows[76 * 75];
  const int n = blockIdx.x;
  const int s = blockIdx.y;
  const int tid = threadIdx.x;
  const int r0 = s * 75;
  const int nrows = (s < 3) ? 76 : 75;
  const float* xb = x + (size_t)n * (T_ * 75) + (size_t)r0 * 75;
  for (int i = tid; i < nrows * 75; i += 256) rows[i] = xb[i];
  __syncthreads();
  if (tid < 75) {
    const int vv = tid / 3, cc = tid % 3;
    const int pj = PARENT_D[vv] * 3 + cc;
    const int j = tid;
    const int chn = cc * 25 + vv;
    float s0 = 0.f, s1 = 0.f, s2 = 0.f, s3 = 0.f;
    float b = rows[j] - rows[pj];
    for (int r = 0; r < 75; ++r) {
      s0 += b; s1 += b * b;
      if (r0 + r < 299) {        // t_bone at t=299 is 0: contributes nothing
        float bn = rows[(r + 1) * 75 + j] - rows[(r + 1) * 75 + pj];
        float tb = bn - b;
        s2 += tb; s3 += tb * tb;
        b = bn;                  // carry: bone[r+1] reused next iteration
      }
    }
    float* sb = stats + (size_t)s * 304;
    atomicAdd(&sb[chn * 2 + 0], s0);
    atomicAdd(&sb[chn * 2 + 1], s1);
    atomicAdd(&sb[150 + chn * 2 + 0], s2);
    atomicAdd(&sb[150 + chn * 2 + 1], s3);
  }
}

// ---- fold BN + layer-1 into bf16 fused frags; convert w1b/w2b to bf16 ----
__global__ void k2_prep(const float* __restrict__ stats,
                        const float* __restrict__ g1, const float* __restrict__ bb1,
                        const float* __restrict__ w1a, const float* __restrict__ b1a,
                        const float* __restrict__ g2, const float* __restrict__ bb2,
                        const float* __restrict__ w2a, const float* __restrict__ b2a,
                        const float* __restrict__ w1b, const float* __restrict__ w2b,
                        unsigned short* __restrict__ wfA, unsigned short* __restrict__ wB) {
  __shared__ float sc[150], sh[150];
  const int tid = threadIdx.x;
  if (tid < 150) {
    int p = tid / 75, c75 = tid % 75;
    float s = 0.f, sq = 0.f;
    for (int k = 0; k < 4; ++k) {         // sum the 4 stat slabs
      s  += stats[k * 304 + p * 150 + c75 * 2 + 0];
      sq += stats[k * 304 + p * 150 + c75 * 2 + 1];
    }
    const float inv = 1.f / 76800.f;
    float mean = s * inv;
    float var = sq * inv - mean * mean;
    var = var < 0.f ? 0.f : var;
    float g  = (p ? g2 : g1)[c75];
    float bb = (p ? bb2 : bb1)[c75];
    float scale = g * rsqrtf(var + 1e-5f);
    sc[tid] = scale;
    sh[tid] = bb - mean * scale;
  }
  __syncthreads();
  for (int idx = tid; idx < 3200; idx += 256) {   // idx = (p*25+v)*64 + o
    int p = idx / 1600, rm = idx % 1600, v = rm / 64, o = rm % 64;
    const float* wa = p ? w2a : w1a;
    const float* ba = p ? b2a : b1a;
    int base = p * 75;
    float sc0 = sc[base + v], sc1 = sc[base + 25 + v], sc2 = sc[base + 50 + v];
    float sh0 = sh[base + v], sh1 = sh[base + 25 + v], sh2 = sh[base + 50 + v];
    float a0 = wa[o * 3 + 0], a1 = wa[o * 3 + 1], a2 = wa[o * 3 + 2];
    float bias = ba[o] + a0 * sh0 + a1 * sh1 + a2 * sh2;
    unsigned short* d = wfA + (size_t)idx * 8;
    d[0] = f2bf(a0 * sc0); d[1] = f2bf(a1 * sc1); d[2] = f2bf(a2 * sc2);
    d[3] = f2bf(bias);
    d[4] = 0; d[5] = 0; d[6] = 0; d[7] = 0;
  }
  for (int idx = tid; idx < 8192; idx += 256)
    wB[idx] = f2bf(idx < 4096 ? w1b[idx] : w2b[idx - 4096]);
}

// ---- main fused kernel: block = (n, chunk), 5 waves = v-group of 5 ----
__launch_bounds__(320)
__global__ void k3_main(const float* __restrict__ x,
                        const unsigned short* __restrict__ wfA,
                        const unsigned short* __restrict__ wB,
                        const float* __restrict__ b1b,
                        const float* __restrict__ b2b,
                        float* __restrict__ out) {
  // staged x rows tbase..tbase+32 (33 x 75 floats); row stride 75 -> bank
  // stride 11 mod 32, gcd(11,32)=1 -> conflict-free per-lane reads.
  __shared__ float Sx[33 * 75];
  // per-wave H buffer: 32 pos x 72 bf16 (rows padded 64->72 to spread LDS banks)
  __shared__ alignas(16) unsigned short Hs[5][32][72];
  const int tid = threadIdx.x;
  const int wave = tid >> 6;
  const int lane = tid & 63;
  const int q   = lane >> 4;
  const int l15 = lane & 15;
  const int p31 = lane & 31;

  const int bid = blockIdx.x;                 // < 12800 = 256*10*5
  const int chunk = bid % 10;
  const int rem = bid / 10;
  const int vg = rem % 5;
  const int n = rem / 5;
  const int v = vg * 5 + wave;                // 5 waves cover 5 consecutive v
  const int pv = PARENT_D[v];
  const int tbase = chunk * 32;
  const int nrows = (chunk < 9) ? 33 : 12;    // chunk 9: rows 288..299 only

  // ---- cooperative coalesced staging: x rows -> LDS (float4) ----
  {
    const float* xb = x + (size_t)n * (T_ * 75) + (size_t)tbase * 75;  // 16B-aligned
    const int total = nrows * 75;
    const int f4 = total >> 2;
    for (int i = tid; i < f4; i += 320)
      ((float4*)Sx)[i] = ((const float4*)xb)[i];
    if (tid < (total & 3)) Sx[(f4 << 2) + tid] = xb[(f4 << 2) + tid];
  }
  __syncthreads();

  // ---- bone / t_bone for position p31 (lanes 0..31 only), from LDS ----
  float b0 = 0.f, b1 = 0.f, b2 = 0.f, d0 = 0.f, d1 = 0.f, d2 = 0.f;
  if (lane < 32) {
    int t = tbase + p31;
    int tr0 = (t < 299 ? t : 299) - tbase;       // clamp OOB tail (stores masked)
    int tr1 = (t + 1 < 299 ? t + 1 : 299) - tbase;  // t=299 -> t_bone = 0 (matches pad)
    const float* r0 = Sx + tr0 * 75;
    const float* r1 = Sx + tr1 * 75;
    float xv0 = r0[v*3+0], xv1 = r0[v*3+1], xv2 = r0[v*3+2];
    float xp0 = r0[pv*3+0], xp1 = r0[pv*3+1], xp2 = r0[pv*3+2];
    float yv0 = r1[v*3+0], yv1 = r1[v*3+1], yv2 = r1[v*3+2];
    float yp0 = r1[pv*3+0], yp1 = r1[pv*3+1], yp2 = r1[pv*3+2];
    b0 = xv0 - xp0; b1 = xv1 - xp1; b2 = xv2 - xp2;
    d0 = (yv0 - yp0) - b0; d1 = (yv1 - yp1) - b1; d2 = (yv2 - yp2) - b2;
  }
  // z of positions 16..31 for pos-tile 1 (needed by q==0 lanes)
  float b0s = __shfl(b0, 16 + l15), b1s = __shfl(b1, 16 + l15), b2s = __shfl(b2, 16 + l15);
  float d0s = __shfl(d0, 16 + l15), d1s = __shfl(d1, 16 + l15), d2s = __shfl(d2, 16 + l15);

  // ---- B-frags for layer 1: B[k][pos], k = {z0,z1,z2,1,0...}; only q==0 nonzero ----
  bf16x8 zf[2][2];
  {
    bf16x8 z8 = {0,0,0,0,0,0,0,0};
    zf[0][0] = z8; zf[0][1] = z8; zf[1][0] = z8; zf[1][1] = z8;
    if (q == 0) {
      zf[0][0][0]=(short)f2bf(b0);  zf[0][0][1]=(short)f2bf(b1);  zf[0][0][2]=(short)f2bf(b2);  zf[0][0][3]=(short)0x3F80;
      zf[0][1][0]=(short)f2bf(b0s); zf[0][1][1]=(short)f2bf(b1s); zf[0][1][2]=(short)f2bf(b2s); zf[0][1][3]=(short)0x3F80;
      zf[1][0][0]=(short)f2bf(d0);  zf[1][0][1]=(short)f2bf(d1);  zf[1][0][2]=(short)f2bf(d2);  zf[1][0][3]=(short)0x3F80;
      zf[1][1][0]=(short)f2bf(d0s); zf[1][1][1]=(short)f2bf(d1s); zf[1][1][2]=(short)f2bf(d2s); zf[1][1][3]=(short)0x3F80;
    }
  }

  // ---- A-frags for layer 1 (fused BN+Wa+bias), only q==0 nonzero ----
  bf16x8 wf[2][4];
#pragma unroll
  for (int p = 0; p < 2; ++p)
#pragma unroll
    for (int to = 0; to < 4; ++to) {
      bf16x8 w = {0,0,0,0,0,0,0,0};
      if (q == 0)
        w = *(const bf16x8*)(wfA + (size_t)((p * 25 + v) * 64 + l15 + 16 * to) * 8);
      wf[p][to] = w;
    }

  f32x4 acc[2][4][2];
  unsigned short (*Hrow)[72] = Hs[wave];

#pragma unroll
  for (int p = 0; p < 2; ++p) {
    // layer 1: D[o-tile][pos-tile] = Wf · Z  (bias via k=3 slot)
    f32x4 D[4][2];
#pragma unroll
    for (int to = 0; to < 4; ++to)
#pragma unroll
      for (int tc = 0; tc < 2; ++tc) {
        f32x4 z4 = {0.f, 0.f, 0.f, 0.f};
        D[to][tc] = __builtin_amdgcn_mfma_f32_16x16x32_bf16(wf[p][to], zf[p][tc], z4, 0, 0, 0);
      }
    // relu -> bf16 -> LDS (H[pos][h]); D row = o_local = q*4+r, col = pos
#pragma unroll
    for (int to = 0; to < 4; ++to)
#pragma unroll
      for (int tc = 0; tc < 2; ++tc) {
        f32x4 dd = D[to][tc];
        uint2 pk;
        pk.x = (unsigned)f2bf(fmaxf(dd[0], 0.f)) | ((unsigned)f2bf(fmaxf(dd[1], 0.f)) << 16);
        pk.y = (unsigned)f2bf(fmaxf(dd[2], 0.f)) | ((unsigned)f2bf(fmaxf(dd[3], 0.f)) << 16);
        *(uint2*)&Hrow[l15 + 16 * tc][16 * to + 4 * q] = pk;
      }
    asm volatile("s_waitcnt lgkmcnt(0)" ::: "memory");  // H writes visible before frag reads

    // layer 2: acc = Wb · H, bias via acc-init
    const unsigned short* wbp = wB + (size_t)p * 4096;
    const float* bias = p ? b2b : b1b;
#pragma unroll
    for (int to = 0; to < 4; ++to) {
      f32x4 bq = *(const f32x4*)(bias + 16 * to + 4 * q);
      acc[p][to][0] = bq;
      acc[p][to][1] = bq;
    }
#pragma unroll
    for (int ks = 0; ks < 2; ++ks) {
      bf16x8 wa2[4];
#pragma unroll
      for (int to = 0; to < 4; ++to)
        wa2[to] = *(const bf16x8*)(wbp + (l15 + 16 * to) * 64 + q * 8 + 32 * ks);
#pragma unroll
      for (int tc = 0; tc < 2; ++tc) {
        bf16x8 hb = *(const bf16x8*)&Hrow[l15 + 16 * tc][q * 8 + 32 * ks];
#pragma unroll
        for (int to = 0; to < 4; ++to)
          acc[p][to][tc] = __builtin_amdgcn_mfma_f32_16x16x32_bf16(wa2[to], hb, acc[p][to][tc], 0, 0, 0);
      }
    }
    asm volatile("s_waitcnt lgkmcnt(0)" ::: "memory");  // reads done before next path rewrites H
  }

  // ---- epilogue: out = relu(acc1) + relu(acc2); D row = o, col = t ----
#pragma unroll
  for (int tc = 0; tc < 2; ++tc) {
    int tpos = tbase + 16 * tc + l15;
    if (tpos < 300) {
#pragma unroll
      for (int to = 0; to < 4; ++to)
#pragma unroll
        for (int r = 0; r < 4; ++r) {
          int o = 16 * to + 4 * q + r;
          float val = fmaxf(acc[0][to][tc][r], 0.f) + fmaxf(acc[1][to][tc][r], 0.f);
          out[(((size_t)n * 64 + o) * 25 + v) * 300 + tpos] = val;
        }
    }
  }
}

extern "C" void kernel_launch(void* const* d_in, const int* in_sizes, int n_in,
                              void* d_out, int out_size, void* d_ws, size_t ws_size,
                              hipStream_t stream) {
  const float* x   = (const float*)d_in[0];
  const float* g1  = (const float*)d_in[1];
  const float* bb1 = (const float*)d_in[2];
  const float* w1a = (const float*)d_in[3];
  const float* b1a = (const float*)d_in[4];
  const float* w1b = (const float*)d_in[5];
  const float* b1b = (const float*)d_in[6];
  const float* g2  = (const float*)d_in[7];
  const float* bb2 = (const float*)d_in[8];
  const float* w2a = (const float*)d_in[9];
  const float* b2a = (const float*)d_in[10];
  const float* w2b = (const float*)d_in[11];
  const float* b2b = (const float*)d_in[12];

  float* stats = (float*)d_ws;                                     // 4 slabs x 304 floats = 1216
  unsigned short* wfA = (unsigned short*)((char*)d_ws + 4864);     // 2*25*64*8 bf16 = 51200 B
  unsigned short* wB  = (unsigned short*)((char*)d_ws + 4864 + 51200);  // 2*64*64 bf16 = 16384 B

  hipLaunchKernelGGL(k0_zero, dim3(5), dim3(256), 0, stream, stats, 1216);
  hipLaunchKernelGGL(k1_stats, dim3(256, 4), dim3(256), 0, stream, x, stats);
  hipLaunchKernelGGL(k2_prep, dim3(1), dim3(256), 0, stream, stats,
                     g1, bb1, w1a, b1a, g2, bb2, w2a, b2a, w1b, w2b, wfA, wB);
  hipLaunchKernelGGL(k3_main, dim3(12800), dim3(320), 0, stream, x, wfA, wB, b1b, b2b, (float*)d_out);
}

// Round 3
// 718.451 us; speedup vs baseline: 1.0527x; 1.0527x over previous
//
#include <hip/hip_runtime.h>
#include <stdint.h>

// out = relu(W1b·relu(Wf1·z1 + bf1) + b1b) + relu(W2b·relu(Wf2·z2 + bf2) + b2b)
// z1 = bone, z2 = t_bone; BN folded into Wf/bf (fused per (path, v)).
// k3 v3: revert to wave-per-(n,v,32t-chunk) (v1 structure, measured faster than
// block-staged v2); gather spread across all 64 lanes (6 loads + 1 shfl instead
// of 12 loads on a half-masked wave).

#define T_ 300

typedef __attribute__((ext_vector_type(8))) short bf16x8;
typedef __attribute__((ext_vector_type(4))) float f32x4;

__device__ __constant__ int PARENT_D[25] = {1,20,20,2,20,4,5,6,20,8,9,10,0,12,13,14,0,16,17,18,20,22,7,24,11};

static __device__ __forceinline__ unsigned short f2bf(float f) {
  unsigned int u = __float_as_uint(f);
  unsigned int r = (u + 0x7FFFu + ((u >> 16) & 1u)) >> 16;  // RNE, no NaN inputs expected
  return (unsigned short)r;
}

__global__ void k0_zero(float* p, int cnt) {
  int i = blockIdx.x * blockDim.x + threadIdx.x;
  if (i < cnt) p[i] = 0.f;
}

// ---- stats: sum/sumsq of bone and t_bone per BN channel (ch = c*25+v) ----
// grid (n=256, s=4): block handles rows [s*75, s*75+75) (+1 boundary row for t_bone).
// bone value carried across iterations -> 2 LDS reads/row instead of 4.
// Atomics go to per-s slabs (stride 304 floats) to cut per-line contention 4x.
__global__ void k1_stats(const float* __restrict__ x, float* __restrict__ stats) {
  __shared__ float rows[76 * 75];
  const int n = blockIdx.x;
  const int s = blockIdx.y;
  const int tid = threadIdx.x;
  const int r0 = s * 75;
  const int nrows = (s < 3) ? 76 : 75;
  const float* xb = x + (size_t)n * (T_ * 75) + (size_t)r0 * 75;
  for (int i = tid; i < nrows * 75; i += 256) rows[i] = xb[i];
  __syncthreads();
  if (tid < 75) {
    const int vv = tid / 3, cc = tid % 3;
    const int pj = PARENT_D[vv] * 3 + cc;
    const int j = tid;
    const int chn = cc * 25 + vv;
    float s0 = 0.f, s1 = 0.f, s2 = 0.f, s3 = 0.f;
    float b = rows[j] - rows[pj];
    for (int r = 0; r < 75; ++r) {
      s0 += b; s1 += b * b;
      if (r0 + r < 299) {        // t_bone at t=299 is 0: contributes nothing
        float bn = rows[(r + 1) * 75 + j] - rows[(r + 1) * 75 + pj];
        float tb = bn - b;
        s2 += tb; s3 += tb * tb;
        b = bn;                  // carry: bone[r+1] reused next iteration
      }
    }
    float* sb = stats + (size_t)s * 304;
    atomicAdd(&sb[chn * 2 + 0], s0);
    atomicAdd(&sb[chn * 2 + 1], s1);
    atomicAdd(&sb[150 + chn * 2 + 0], s2);
    atomicAdd(&sb[150 + chn * 2 + 1], s3);
  }
}

// ---- fold BN + layer-1 into bf16 fused frags; convert w1b/w2b to bf16 ----
__global__ void k2_prep(const float* __restrict__ stats,
                        const float* __restrict__ g1, const float* __restrict__ bb1,
                        const float* __restrict__ w1a, const float* __restrict__ b1a,
                        const float* __restrict__ g2, const float* __restrict__ bb2,
                        const float* __restrict__ w2a, const float* __restrict__ b2a,
                        const float* __restrict__ w1b, const float* __restrict__ w2b,
                        unsigned short* __restrict__ wfA, unsigned short* __restrict__ wB) {
  __shared__ float sc[150], sh[150];
  const int tid = threadIdx.x;
  if (tid < 150) {
    int p = tid / 75, c75 = tid % 75;
    float s = 0.f, sq = 0.f;
    for (int k = 0; k < 4; ++k) {         // sum the 4 stat slabs
      s  += stats[k * 304 + p * 150 + c75 * 2 + 0];
      sq += stats[k * 304 + p * 150 + c75 * 2 + 1];
    }
    const float inv = 1.f / 76800.f;
    float mean = s * inv;
    float var = sq * inv - mean * mean;
    var = var < 0.f ? 0.f : var;
    float g  = (p ? g2 : g1)[c75];
    float bb = (p ? bb2 : bb1)[c75];
    float scale = g * rsqrtf(var + 1e-5f);
    sc[tid] = scale;
    sh[tid] = bb - mean * scale;
  }
  __syncthreads();
  for (int idx = tid; idx < 3200; idx += 256) {   // idx = (p*25+v)*64 + o
    int p = idx / 1600, rm = idx % 1600, v = rm / 64, o = rm % 64;
    const float* wa = p ? w2a : w1a;
    const float* ba = p ? b2a : b1a;
    int base = p * 75;
    float sc0 = sc[base + v], sc1 = sc[base + 25 + v], sc2 = sc[base + 50 + v];
    float sh0 = sh[base + v], sh1 = sh[base + 25 + v], sh2 = sh[base + 50 + v];
    float a0 = wa[o * 3 + 0], a1 = wa[o * 3 + 1], a2 = wa[o * 3 + 2];
    float bias = ba[o] + a0 * sh0 + a1 * sh1 + a2 * sh2;
    unsigned short* d = wfA + (size_t)idx * 8;
    d[0] = f2bf(a0 * sc0); d[1] = f2bf(a1 * sc1); d[2] = f2bf(a2 * sc2);
    d[3] = f2bf(bias);
    d[4] = 0; d[5] = 0; d[6] = 0; d[7] = 0;
  }
  for (int idx = tid; idx < 8192; idx += 256)
    wB[idx] = f2bf(idx < 4096 ? w1b[idx] : w2b[idx - 4096]);
}

// ---- main fused kernel: one wave per (n, v, 32-t chunk) ----
__launch_bounds__(256, 2)
__global__ void k3_main(const float* __restrict__ x,
                        const unsigned short* __restrict__ wfA,
                        const unsigned short* __restrict__ wB,
                        const float* __restrict__ b1b,
                        const float* __restrict__ b2b,
                        float* __restrict__ out) {
  // per-wave H buffer: 32 pos x 72 bf16 (rows padded 64->72 to spread LDS banks)
  __shared__ alignas(16) unsigned short Hs[4][32][72];
  const int tid = threadIdx.x;
  const int wave = tid >> 6;
  const int lane = tid & 63;
  const int q   = lane >> 4;
  const int l15 = lane & 15;
  const int p31 = lane & 31;

  const int wid = blockIdx.x * 4 + wave;      // < 64000 = 256*25*10
  const int chunk = wid % 10;
  const int rem = wid / 10;
  const int v = rem % 25;
  const int n = rem / 25;
  const int pv = PARENT_D[v];
  const int tbase = chunk * 32;

  // ---- bone / t_bone gather, spread over all 64 lanes ----
  // lanes 0..31 load row t = tbase+p31; lanes 32..63 load row t+1.
  // bone computed per-lane; bone[t+1] pulled from the upper half via shfl.
  float b0, b1, b2, d0, d1, d2;
  {
    int t = tbase + p31 + (lane >> 5);
    int tr = t < 299 ? t : 299;            // clamp OOB tail (stores masked);
                                           // t=299 -> both halves read row 299 -> t_bone = 0 (matches pad)
    const float* r = x + (size_t)n * (T_ * 75) + (size_t)tr * 75;
    float u0 = r[v*3+0],  u1 = r[v*3+1],  u2 = r[v*3+2];
    float w0 = r[pv*3+0], w1 = r[pv*3+1], w2 = r[pv*3+2];
    b0 = u0 - w0; b1 = u1 - w1; b2 = u2 - w2;
    float n0 = __shfl(b0, p31 + 32), n1 = __shfl(b1, p31 + 32), n2 = __shfl(b2, p31 + 32);
    d0 = n0 - b0; d1 = n1 - b1; d2 = n2 - b2;   // valid on lanes 0..31 (upper half unused)
  }
  // z of positions 16..31 for pos-tile 1 (needed by q==0 lanes)
  float b0s = __shfl(b0, 16 + l15), b1s = __shfl(b1, 16 + l15), b2s = __shfl(b2, 16 + l15);
  float d0s = __shfl(d0, 16 + l15), d1s = __shfl(d1, 16 + l15), d2s = __shfl(d2, 16 + l15);

  // ---- B-frags for layer 1: B[k][pos], k = {z0,z1,z2,1,0...}; only q==0 nonzero ----
  bf16x8 zf[2][2];
  {
    bf16x8 z8 = {0,0,0,0,0,0,0,0};
    zf[0][0] = z8; zf[0][1] = z8; zf[1][0] = z8; zf[1][1] = z8;
    if (q == 0) {
      zf[0][0][0]=(short)f2bf(b0);  zf[0][0][1]=(short)f2bf(b1);  zf[0][0][2]=(short)f2bf(b2);  zf[0][0][3]=(short)0x3F80;
      zf[0][1][0]=(short)f2bf(b0s); zf[0][1][1]=(short)f2bf(b1s); zf[0][1][2]=(short)f2bf(b2s); zf[0][1][3]=(short)0x3F80;
      zf[1][0][0]=(short)f2bf(d0);  zf[1][0][1]=(short)f2bf(d1);  zf[1][0][2]=(short)f2bf(d2);  zf[1][0][3]=(short)0x3F80;
      zf[1][1][0]=(short)f2bf(d0s); zf[1][1][1]=(short)f2bf(d1s); zf[1][1][2]=(short)f2bf(d2s); zf[1][1][3]=(short)0x3F80;
    }
  }

  // ---- A-frags for layer 1 (fused BN+Wa+bias), only q==0 nonzero ----
  bf16x8 wf[2][4];
#pragma unroll
  for (int p = 0; p < 2; ++p)
#pragma unroll
    for (int to = 0; to < 4; ++to) {
      bf16x8 w = {0,0,0,0,0,0,0,0};
      if (q == 0)
        w = *(const bf16x8*)(wfA + (size_t)((p * 25 + v) * 64 + l15 + 16 * to) * 8);
      wf[p][to] = w;
    }

  f32x4 acc[2][4][2];
  unsigned short (*Hrow)[72] = Hs[wave];

#pragma unroll
  for (int p = 0; p < 2; ++p) {
    // layer 1: D[o-tile][pos-tile] = Wf · Z  (bias via k=3 slot)
    f32x4 D[4][2];
#pragma unroll
    for (int to = 0; to < 4; ++to)
#pragma unroll
      for (int tc = 0; tc < 2; ++tc) {
        f32x4 z4 = {0.f, 0.f, 0.f, 0.f};
        D[to][tc] = __builtin_amdgcn_mfma_f32_16x16x32_bf16(wf[p][to], zf[p][tc], z4, 0, 0, 0);
      }
    // relu -> bf16 -> LDS (H[pos][h]); D row = o_local = q*4+r, col = pos
#pragma unroll
    for (int to = 0; to < 4; ++to)
#pragma unroll
      for (int tc = 0; tc < 2; ++tc) {
        f32x4 dd = D[to][tc];
        uint2 pk;
        pk.x = (unsigned)f2bf(fmaxf(dd[0], 0.f)) | ((unsigned)f2bf(fmaxf(dd[1], 0.f)) << 16);
        pk.y = (unsigned)f2bf(fmaxf(dd[2], 0.f)) | ((unsigned)f2bf(fmaxf(dd[3], 0.f)) << 16);
        *(uint2*)&Hrow[l15 + 16 * tc][16 * to + 4 * q] = pk;
      }
    asm volatile("s_waitcnt lgkmcnt(0)" ::: "memory");  // H writes visible before frag reads

    // layer 2: acc = Wb · H, bias via acc-init
    const unsigned short* wbp = wB + (size_t)p * 4096;
    const float* bias = p ? b2b : b1b;
#pragma unroll
    for (int to = 0; to < 4; ++to) {
      f32x4 bq = *(const f32x4*)(bias + 16 * to + 4 * q);
      acc[p][to][0] = bq;
      acc[p][to][1] = bq;
    }
#pragma unroll
    for (int ks = 0; ks < 2; ++ks) {
      bf16x8 wa2[4];
#pragma unroll
      for (int to = 0; to < 4; ++to)
        wa2[to] = *(const bf16x8*)(wbp + (l15 + 16 * to) * 64 + q * 8 + 32 * ks);
#pragma unroll
      for (int tc = 0; tc < 2; ++tc) {
        bf16x8 hb = *(const bf16x8*)&Hrow[l15 + 16 * tc][q * 8 + 32 * ks];
#pragma unroll
        for (int to = 0; to < 4; ++to)
          acc[p][to][tc] = __builtin_amdgcn_mfma_f32_16x16x32_bf16(wa2[to], hb, acc[p][to][tc], 0, 0, 0);
      }
    }
    asm volatile("s_waitcnt lgkmcnt(0)" ::: "memory");  // reads done before next path rewrites H
  }

  // ---- epilogue: out = relu(acc1) + relu(acc2); D row = o, col = t ----
#pragma unroll
  for (int tc = 0; tc < 2; ++tc) {
    int tpos = tbase + 16 * tc + l15;
    if (tpos < 300) {
#pragma unroll
      for (int to = 0; to < 4; ++to)
#pragma unroll
        for (int r = 0; r < 4; ++r) {
          int o = 16 * to + 4 * q + r;
          float val = fmaxf(acc[0][to][tc][r], 0.f) + fmaxf(acc[1][to][tc][r], 0.f);
          out[(((size_t)n * 64 + o) * 25 + v) * 300 + tpos] = val;
        }
    }
  }
}

extern "C" void kernel_launch(void* const* d_in, const int* in_sizes, int n_in,
                              void* d_out, int out_size, void* d_ws, size_t ws_size,
                              hipStream_t stream) {
  const float* x   = (const float*)d_in[0];
  const float* g1  = (const float*)d_in[1];
  const float* bb1 = (const float*)d_in[2];
  const float* w1a = (const float*)d_in[3];
  const float* b1a = (const float*)d_in[4];
  const float* w1b = (const float*)d_in[5];
  const float* b1b = (const float*)d_in[6];
  const float* g2  = (const float*)d_in[7];
  const float* bb2 = (const float*)d_in[8];
  const float* w2a = (const float*)d_in[9];
  const float* b2a = (const float*)d_in[10];
  const float* w2b = (const float*)d_in[11];
  const float* b2b = (const float*)d_in[12];

  float* stats = (float*)d_ws;                                     // 4 slabs x 304 floats = 1216
  unsigned short* wfA = (unsigned short*)((char*)d_ws + 4864);     // 2*25*64*8 bf16 = 51200 B
  unsigned short* wB  = (unsigned short*)((char*)d_ws + 4864 + 51200);  // 2*64*64 bf16 = 16384 B

  hipLaunchKernelGGL(k0_zero, dim3(5), dim3(256), 0, stream, stats, 1216);
  hipLaunchKernelGGL(k1_stats, dim3(256, 4), dim3(256), 0, stream, x, stats);
  hipLaunchKernelGGL(k2_prep, dim3(1), dim3(256), 0, stream, stats,
                     g1, bb1, w1a, b1a, g2, bb2, w2a, b2a, w1b, w2b, wfA, wB);
  hipLaunchKernelGGL(k3_main, dim3(16000), dim3(256), 0, stream, x, wfA, wB, b1b, b2b, (float*)d_out);
}